// Round 8
// baseline (412.915 us; speedup 1.0000x reference)
//
#include <hip/hip_runtime.h>

#define DD 50176          // h*w
#define NB 16             // batches
#define NK 64             // k masks
#define TK 64             // k-tile width

// ---------------------------------------------------------------------------
// Kernel 1: split-K partial GEMM, 256 threads, 4x4 register tile/thread.
// T14 register double-buffer; norms accumulated from staging registers.
// LDS transposed [kk][col] with granule skew col=(row+4*(kk>>2))&63.
// ---------------------------------------------------------------------------
template <int NSPLIT, int NTILE>
__global__ __launch_bounds__(256) void gemm_partial(const float* __restrict__ A,
                                                    const float* __restrict__ B,
                                                    float* __restrict__ ws) {
  const int s = blockIdx.x;     // split
  const int b = blockIdx.y;     // batch
  const float* Ab = A + (size_t)b * NK * DD;
  const float* Bb = B + (size_t)b * NK * DD;
  __shared__ float As[TK * 64];
  __shared__ float Bs[TK * 64];
  const int tid = threadIdx.x;
  const int ti = tid & 15;      // output row-quad
  const int tj = tid >> 4;      // output col-quad
  const int kq = tid & 15;      // staging: k-granule 0..15
  const int r0 = tid >> 4;      // staging: row base 0..15

  float c[4][4] = {{0.f, 0.f, 0.f, 0.f}, {0.f, 0.f, 0.f, 0.f},
                   {0.f, 0.f, 0.f, 0.f}, {0.f, 0.f, 0.f, 0.f}};
  float a2p[4] = {0.f, 0.f, 0.f, 0.f};
  float b2p[4] = {0.f, 0.f, 0.f, 0.f};
  float4 avr[4], bvr[4];

  {
    const int k0 = s * NTILE * TK;
#pragma unroll
    for (int f = 0; f < 4; ++f) {
      const int r = f * 16 + r0;
      avr[f] = *reinterpret_cast<const float4*>(Ab + (size_t)r * DD + k0 + kq * 4);
      bvr[f] = *reinterpret_cast<const float4*>(Bb + (size_t)r * DD + k0 + kq * 4);
    }
  }

  for (int t = 0; t < NTILE; ++t) {
    __syncthreads();
#pragma unroll
    for (int f = 0; f < 4; ++f) {
      const int r = f * 16 + r0;
      const int col = (r + 4 * kq) & 63;
      const float4 av = avr[f];
      const float4 bv = bvr[f];
      As[(kq * 4 + 0) * 64 + col] = av.x;
      As[(kq * 4 + 1) * 64 + col] = av.y;
      As[(kq * 4 + 2) * 64 + col] = av.z;
      As[(kq * 4 + 3) * 64 + col] = av.w;
      Bs[(kq * 4 + 0) * 64 + col] = bv.x;
      Bs[(kq * 4 + 1) * 64 + col] = bv.y;
      Bs[(kq * 4 + 2) * 64 + col] = bv.z;
      Bs[(kq * 4 + 3) * 64 + col] = bv.w;
      a2p[f] = fmaf(av.x, av.x, a2p[f]); a2p[f] = fmaf(av.y, av.y, a2p[f]);
      a2p[f] = fmaf(av.z, av.z, a2p[f]); a2p[f] = fmaf(av.w, av.w, a2p[f]);
      b2p[f] = fmaf(bv.x, bv.x, b2p[f]); b2p[f] = fmaf(bv.y, bv.y, b2p[f]);
      b2p[f] = fmaf(bv.z, bv.z, b2p[f]); b2p[f] = fmaf(bv.w, bv.w, b2p[f]);
    }
    __syncthreads();

    if (t + 1 < NTILE) {
      const int k0 = (s * NTILE + t + 1) * TK;
#pragma unroll
      for (int f = 0; f < 4; ++f) {
        const int r = f * 16 + r0;
        avr[f] = *reinterpret_cast<const float4*>(Ab + (size_t)r * DD + k0 + kq * 4);
        bvr[f] = *reinterpret_cast<const float4*>(Bb + (size_t)r * DD + k0 + kq * 4);
      }
    }

#pragma unroll 8
    for (int kk = 0; kk < TK; ++kk) {
      const int g = 4 * (kk >> 2);
      const float4 a4 = *reinterpret_cast<const float4*>(&As[kk * 64 + ((4 * ti + g) & 63)]);
      const float4 b4 = *reinterpret_cast<const float4*>(&Bs[kk * 64 + ((4 * tj + g) & 63)]);
      const float ar[4] = {a4.x, a4.y, a4.z, a4.w};
      const float br[4] = {b4.x, b4.y, b4.z, b4.w};
#pragma unroll
      for (int r = 0; r < 4; ++r)
#pragma unroll
        for (int cc = 0; cc < 4; ++cc)
          c[r][cc] = fmaf(ar[r], br[cc], c[r][cc]);
    }
  }

  float* Pab = ws + (size_t)(b * NSPLIT + s) * 4096;
#pragma unroll
  for (int r = 0; r < 4; ++r) {
    *reinterpret_cast<float4*>(Pab + (ti * 4 + r) * 64 + tj * 4) =
        make_float4(c[r][0], c[r][1], c[r][2], c[r][3]);
  }

#pragma unroll
  for (int f = 0; f < 4; ++f) {
#pragma unroll
    for (int off = 1; off < 16; off <<= 1) {
      a2p[f] += __shfl_xor(a2p[f], off, 64);
      b2p[f] += __shfl_xor(b2p[f], off, 64);
    }
  }
  if (kq == 0) {
    float* Pa2 = ws + (size_t)NB * NSPLIT * 4096 + (size_t)(b * NSPLIT + s) * 64;
    float* Pb2 = Pa2 + (size_t)NB * NSPLIT * 64;
#pragma unroll
    for (int f = 0; f < 4; ++f) {
      Pa2[f * 16 + r0] = a2p[f];
      Pb2[f * 16 + r0] = b2p[f];
    }
  }
}

// ---------------------------------------------------------------------------
// Kernel 2: parallel cost build. 16 slices x 16 batches = 256 blocks.
// ---------------------------------------------------------------------------
template <int NSPLIT>
__global__ __launch_bounds__(256) void reduce_cost(const float* __restrict__ ws,
                                                   double* __restrict__ costg) {
  const int slice = blockIdx.x;  // 0..15
  const int b = blockIdx.y;
  const int tid = threadIdx.x;
  __shared__ double a2s[4], b2s[64];
  const size_t pa2 = (size_t)NB * NSPLIT * 4096;
  const size_t pb2 = pa2 + (size_t)NB * NSPLIT * 64;

  if (tid < 64) {
    double s = 0.0;
    for (int sp = 0; sp < NSPLIT; ++sp)
      s += (double)ws[pb2 + (size_t)(b * NSPLIT + sp) * 64 + tid];
    b2s[tid] = s;
  } else if (tid < 68) {
    const int r = slice * 4 + (tid - 64);
    double s = 0.0;
    for (int sp = 0; sp < NSPLIT; ++sp)
      s += (double)ws[pa2 + (size_t)(b * NSPLIT + sp) * 64 + r];
    a2s[tid - 64] = s;
  }

  const int elem = slice * 256 + tid;   // 0..4095
  double acc = 0.0;
  for (int sp = 0; sp < NSPLIT; ++sp)
    acc += (double)ws[(size_t)(b * NSPLIT + sp) * 4096 + elem];
  __syncthreads();

  const int ii = tid >> 6;              // row within slice
  const int j = tid & 63;
  const double c2 = a2s[ii] + b2s[j] - 2.0 * acc;
  costg[(size_t)b * 4096 + elem] = sqrt(c2 > 0.0 ? c2 : 0.0);
}

// ---------------------------------------------------------------------------
// Kernel 3: pure solver. 16 blocks x 64 threads (1 wave). Cost in LDS.
// Col-reduction init + greedy, JV reduction transfer, Augmenting Row
// Reduction (kick-chains), register Dijkstra. Exact min via hi/lo split
// 32-bit DPP reduce on monotone-u64 keys (hi word first; lo resolved by
// readlane or a second 32-bit reduce on hi-ties). First-index tie-break.
// ---------------------------------------------------------------------------
__device__ __forceinline__ double readlane_d(double x, int lane) {
  const int lo = __builtin_amdgcn_readlane(__double2loint(x), lane);
  const int hi = __builtin_amdgcn_readlane(__double2hiint(x), lane);
  return __hiloint2double(hi, lo);
}

template <int CTRL, int RMASK>
__device__ __forceinline__ unsigned dpp32_step(unsigned k) {
  const unsigned o = (unsigned)__builtin_amdgcn_update_dpp(
      -1, (int)k, CTRL, RMASK, 0xf, false);
  return o < k ? o : k;
}
// 64-lane u32 min, result broadcast (uniform)
__device__ __forceinline__ unsigned dpp_min32_bcast(unsigned k) {
  k = dpp32_step<0x111, 0xf>(k);   // row_shr:1
  k = dpp32_step<0x112, 0xf>(k);   // row_shr:2
  k = dpp32_step<0x114, 0xf>(k);   // row_shr:4
  k = dpp32_step<0x118, 0xf>(k);   // row_shr:8
  k = dpp32_step<0x142, 0xa>(k);   // row_bcast:15
  k = dpp32_step<0x143, 0xc>(k);   // row_bcast:31
  return (unsigned)__builtin_amdgcn_readlane((int)k, 63);
}

__device__ __forceinline__ unsigned long long pack_key(double x) {
  const unsigned long long cb = (unsigned long long)__double_as_longlong(x);
  return cb ^ ((unsigned long long)((long long)cb >> 63) | 0x8000000000000000ULL);
}
__device__ __forceinline__ double unpack_key(unsigned long long k) {
  const unsigned long long SGN = 0x8000000000000000ULL;
  const unsigned long long mbits = (k & SGN) ? (k ^ SGN) : ~k;
  return __longlong_as_double((long long)mbits);
}

// exact 64-lane min of monotone-u64 keys; uniform result.
__device__ __forceinline__ unsigned long long wave_min_exact(unsigned long long key,
                                                             int l) {
  const unsigned khi = (unsigned)(key >> 32);
  const unsigned mhi = dpp_min32_bcast(khi);
  const unsigned long long tied = __ballot(khi == mhi);
  unsigned mlo;
  if (__popcll(tied) == 1) {
    mlo = (unsigned)__builtin_amdgcn_readlane((int)(unsigned)key,
                                              __ffsll(tied) - 1);
  } else {
    const unsigned cl = ((tied >> l) & 1ULL) ? (unsigned)key : 0xFFFFFFFFu;
    mlo = dpp_min32_bcast(cl);
  }
  return ((unsigned long long)mhi << 32) | mlo;
}

__global__ __launch_bounds__(64) void lsa_solve(const double* __restrict__ costg,
                                                int* __restrict__ out) {
  const int b = blockIdx.x;
  __shared__ double costd[64 * 64];
  const int tid = threadIdx.x;

  for (int e = tid; e < 4096; e += 64)
    costd[e] = costg[(size_t)b * 4096 + e];
  __syncthreads();

  const int l = tid;                 // lane l <-> column l+1, row l+1
  const double INFD = 1e30;

  // ---- column reduction: v[j] = min_i c[i,j]; greedy tight matching, u=0
  double cmin = costd[l];
  int cargmin = 0;
#pragma unroll 8
  for (int r = 1; r < 64; ++r) {
    const double cv = costd[r * 64 + l];
    if (cv < cmin) { cmin = cv; cargmin = r; }
  }
  double v_l = cmin;
  double u_l = 0.0;
  int p_l = 0;                       // row matched to column l+1 (0 = free)
  int colof_l = 0;                   // column matched to row l+1 (0 = free)
  unsigned long long rowused = 0ULL;
  for (int j = 0; j < 64; ++j) {
    const int rj = __builtin_amdgcn_readlane(cargmin, j);
    if (!((rowused >> rj) & 1ULL)) {
      rowused |= 1ULL << rj;
      if (l == j) p_l = rj + 1;
      if (l == rj) colof_l = j + 1;
    }
  }
  unsigned long long freemask = ~rowused;  // bit r-1 = row r unassigned

  // ---- JV reduction transfer: for each init-matched row ri (u was 0),
  // u[ri] = min_{j != j1}(c[ri][j] - v[j]); v[j1] -= u[ri].
  // Keeps feasibility; matched edge stays tight.
  {
    unsigned long long rm = rowused;
    while (rm) {
      const int ri = __ffsll(rm) - 1;          // 0-indexed matched row
      rm &= rm - 1;
      const int j1 = __builtin_amdgcn_readlane(colof_l, ri) - 1;  // its col
      const double red = costd[ri * 64 + l] - v_l;
      const unsigned long long k1 = (l == j1) ? pack_key(INFD) : pack_key(red);
      const unsigned long long mk = wave_min_exact(k1, l);
      const double rmin = unpack_key(mk);
      if (l == ri) u_l = rmin;
      if (l == j1) v_l -= rmin;
    }
  }

  // ---- Augmenting Row Reduction (JV)
  for (int pass = 0; pass < 2; ++pass) {
    unsigned long long m = freemask;
    while (m) {
      int ir = __ffsll(m);           // 1-indexed free row
      m &= m - 1;
      for (int chain = 0; chain < 32; ++chain) {
        if (!((freemask >> (ir - 1)) & 1ULL)) break;
        const double cur = costd[(ir - 1) * 64 + l] - v_l;
        const unsigned long long key1 = pack_key(cur);
        const unsigned long long mk1 = wave_min_exact(key1, l);
        const double u1 = unpack_key(mk1);
        const int j1 = __ffsll(__ballot(key1 == mk1)) - 1;
        const unsigned long long key2 = (l == j1) ? pack_key(INFD) : key1;
        const unsigned long long mk2 = wave_min_exact(key2, l);
        const double u2 = unpack_key(mk2);
        if (l == ir - 1) u_l = u2;
        const bool strict = (u1 < u2);
        if (strict && l == j1) v_l -= (u2 - u1);
        const int k = __builtin_amdgcn_readlane(p_l, j1);  // occupant of col j1
        if (strict || k == 0) {
          if (l == j1) p_l = ir;
          if (l == ir - 1) colof_l = j1 + 1;
          freemask &= ~(1ULL << (ir - 1));
          if (k != 0) {
            if (l == k - 1) colof_l = 0;
            freemask |= 1ULL << (k - 1);
            if (strict) { ir = k; continue; }  // retry kicked row
          }
          break;
        } else {
          break;                     // tie & occupied: leave for Dijkstra
        }
      }
    }
  }

  // ---- shortest augmenting path for remaining free rows
  for (int i_row = 1; i_row <= 64; ++i_row) {
    if (!((freemask >> (i_row - 1)) & 1ULL)) continue;
    double minv = INFD;
    int way_l = 0;
    bool used = false;
    int j0 = 0;

    while (true) {
      const int i0 = (j0 == 0) ? i_row : __builtin_amdgcn_readlane(p_l, j0 - 1);
      if (i0 == 0) break;
      if (j0 > 0 && l == j0 - 1) used = true;
      const double ui0 = readlane_d(u_l, i0 - 1);
      const double cur = costd[(i0 - 1) * 64 + l] - ui0 - v_l;
      if (!used && cur < minv) { minv = cur; way_l = j0; }
      const double cand = used ? INFD : minv;

      const unsigned long long key = pack_key(cand);
      const unsigned long long mkey = wave_min_exact(key, l);
      const double delta = unpack_key(mkey);
      const int jmin = __ffsll(__ballot(key == mkey)) - 1;

      if (used) v_l -= delta; else minv -= delta;
      const unsigned long long um = __ballot(used);
      const bool addu = (l + 1 == i_row) ||
                        (colof_l != 0 && ((um >> (colof_l - 1)) & 1ULL));
      if (addu) u_l += delta;
      j0 = jmin + 1;
    }

    while (j0 != 0) {
      const int j1 = __builtin_amdgcn_readlane(way_l, j0 - 1);
      const int pj1 = (j1 == 0) ? i_row : __builtin_amdgcn_readlane(p_l, j1 - 1);
      if (l == j0 - 1) p_l = pj1;
      if (l == pj1 - 1) colof_l = j0;
      j0 = j1;
    }
  }

  out[b * NK + l] = l;                       // inds  (arange)
  out[NB * NK + b * NK + l] = colof_l - 1;   // inds2 (col of row l+1)
}

extern "C" void kernel_launch(void* const* d_in, const int* in_sizes, int n_in,
                              void* d_out, int out_size, void* d_ws, size_t ws_size,
                              hipStream_t stream) {
  const float* A = (const float*)d_in[0];   // outputs [16,64,50176] fp32
  const float* B = (const float*)d_in[1];   // targets [16,64,50176] fp32
  float* ws = (float*)d_ws;
  int* out = (int*)d_out;                   // 2048 int32: [inds | inds2]

  // floats used by partials: NB*NSPLIT*(4096+128); cost doubles appended.
  const size_t f112 = (size_t)NB * 112 * 4224;
  const size_t need112 = f112 * 4 + (size_t)NB * 4096 * 8;

  if (ws_size >= need112) {
    double* costg = (double*)(ws + f112);
    gemm_partial<112, 7><<<dim3(112, NB), 256, 0, stream>>>(A, B, ws);
    reduce_cost<112><<<dim3(16, NB), 256, 0, stream>>>(ws, costg);
    lsa_solve<<<NB, 64, 0, stream>>>(costg, out);
  } else {
    const size_t f49 = (size_t)NB * 49 * 4224;
    double* costg = (double*)(ws + f49);
    gemm_partial<49, 16><<<dim3(49, NB), 256, 0, stream>>>(A, B, ws);
    reduce_cost<49><<<dim3(16, NB), 256, 0, stream>>>(ws, costg);
    lsa_solve<<<NB, 64, 0, stream>>>(costg, out);
  }
}

// Round 9
// 346.181 us; speedup vs baseline: 1.1928x; 1.1928x over previous
//
#include <hip/hip_runtime.h>

#define DD 50176          // h*w
#define NB 16             // batches
#define NK 64             // k masks
#define TK 64             // k-tile width

// ---------------------------------------------------------------------------
// Kernel 1: split-K partial GEMM, 256 threads, 4x4 register tile/thread.
// T14 register double-buffer; norms accumulated from staging registers.
// LDS transposed [kk][col] with granule skew col=(row+4*(kk>>2))&63.
// ---------------------------------------------------------------------------
template <int NSPLIT, int NTILE>
__global__ __launch_bounds__(256) void gemm_partial(const float* __restrict__ A,
                                                    const float* __restrict__ B,
                                                    float* __restrict__ ws) {
  const int s = blockIdx.x;     // split
  const int b = blockIdx.y;     // batch
  const float* Ab = A + (size_t)b * NK * DD;
  const float* Bb = B + (size_t)b * NK * DD;
  __shared__ float As[TK * 64];
  __shared__ float Bs[TK * 64];
  const int tid = threadIdx.x;
  const int ti = tid & 15;      // output row-quad
  const int tj = tid >> 4;      // output col-quad
  const int kq = tid & 15;      // staging: k-granule 0..15
  const int r0 = tid >> 4;      // staging: row base 0..15

  float c[4][4] = {{0.f, 0.f, 0.f, 0.f}, {0.f, 0.f, 0.f, 0.f},
                   {0.f, 0.f, 0.f, 0.f}, {0.f, 0.f, 0.f, 0.f}};
  float a2p[4] = {0.f, 0.f, 0.f, 0.f};
  float b2p[4] = {0.f, 0.f, 0.f, 0.f};
  float4 avr[4], bvr[4];

  {
    const int k0 = s * NTILE * TK;
#pragma unroll
    for (int f = 0; f < 4; ++f) {
      const int r = f * 16 + r0;
      avr[f] = *reinterpret_cast<const float4*>(Ab + (size_t)r * DD + k0 + kq * 4);
      bvr[f] = *reinterpret_cast<const float4*>(Bb + (size_t)r * DD + k0 + kq * 4);
    }
  }

  for (int t = 0; t < NTILE; ++t) {
    __syncthreads();
#pragma unroll
    for (int f = 0; f < 4; ++f) {
      const int r = f * 16 + r0;
      const int col = (r + 4 * kq) & 63;
      const float4 av = avr[f];
      const float4 bv = bvr[f];
      As[(kq * 4 + 0) * 64 + col] = av.x;
      As[(kq * 4 + 1) * 64 + col] = av.y;
      As[(kq * 4 + 2) * 64 + col] = av.z;
      As[(kq * 4 + 3) * 64 + col] = av.w;
      Bs[(kq * 4 + 0) * 64 + col] = bv.x;
      Bs[(kq * 4 + 1) * 64 + col] = bv.y;
      Bs[(kq * 4 + 2) * 64 + col] = bv.z;
      Bs[(kq * 4 + 3) * 64 + col] = bv.w;
      a2p[f] = fmaf(av.x, av.x, a2p[f]); a2p[f] = fmaf(av.y, av.y, a2p[f]);
      a2p[f] = fmaf(av.z, av.z, a2p[f]); a2p[f] = fmaf(av.w, av.w, a2p[f]);
      b2p[f] = fmaf(bv.x, bv.x, b2p[f]); b2p[f] = fmaf(bv.y, bv.y, b2p[f]);
      b2p[f] = fmaf(bv.z, bv.z, b2p[f]); b2p[f] = fmaf(bv.w, bv.w, b2p[f]);
    }
    __syncthreads();

    if (t + 1 < NTILE) {
      const int k0 = (s * NTILE + t + 1) * TK;
#pragma unroll
      for (int f = 0; f < 4; ++f) {
        const int r = f * 16 + r0;
        avr[f] = *reinterpret_cast<const float4*>(Ab + (size_t)r * DD + k0 + kq * 4);
        bvr[f] = *reinterpret_cast<const float4*>(Bb + (size_t)r * DD + k0 + kq * 4);
      }
    }

#pragma unroll 8
    for (int kk = 0; kk < TK; ++kk) {
      const int g = 4 * (kk >> 2);
      const float4 a4 = *reinterpret_cast<const float4*>(&As[kk * 64 + ((4 * ti + g) & 63)]);
      const float4 b4 = *reinterpret_cast<const float4*>(&Bs[kk * 64 + ((4 * tj + g) & 63)]);
      const float ar[4] = {a4.x, a4.y, a4.z, a4.w};
      const float br[4] = {b4.x, b4.y, b4.z, b4.w};
#pragma unroll
      for (int r = 0; r < 4; ++r)
#pragma unroll
        for (int cc = 0; cc < 4; ++cc)
          c[r][cc] = fmaf(ar[r], br[cc], c[r][cc]);
    }
  }

  float* Pab = ws + (size_t)(b * NSPLIT + s) * 4096;
#pragma unroll
  for (int r = 0; r < 4; ++r) {
    *reinterpret_cast<float4*>(Pab + (ti * 4 + r) * 64 + tj * 4) =
        make_float4(c[r][0], c[r][1], c[r][2], c[r][3]);
  }

#pragma unroll
  for (int f = 0; f < 4; ++f) {
#pragma unroll
    for (int off = 1; off < 16; off <<= 1) {
      a2p[f] += __shfl_xor(a2p[f], off, 64);
      b2p[f] += __shfl_xor(b2p[f], off, 64);
    }
  }
  if (kq == 0) {
    float* Pa2 = ws + (size_t)NB * NSPLIT * 4096 + (size_t)(b * NSPLIT + s) * 64;
    float* Pb2 = Pa2 + (size_t)NB * NSPLIT * 64;
#pragma unroll
    for (int f = 0; f < 4; ++f) {
      Pa2[f * 16 + r0] = a2p[f];
      Pb2[f * 16 + r0] = b2p[f];
    }
  }
}

// ---------------------------------------------------------------------------
// Kernel 2: parallel cost build. 16 slices x 16 batches = 256 blocks.
// ---------------------------------------------------------------------------
template <int NSPLIT>
__global__ __launch_bounds__(256) void reduce_cost(const float* __restrict__ ws,
                                                   double* __restrict__ costg) {
  const int slice = blockIdx.x;  // 0..15
  const int b = blockIdx.y;
  const int tid = threadIdx.x;
  __shared__ double a2s[4], b2s[64];
  const size_t pa2 = (size_t)NB * NSPLIT * 4096;
  const size_t pb2 = pa2 + (size_t)NB * NSPLIT * 64;

  if (tid < 64) {
    double s = 0.0;
    for (int sp = 0; sp < NSPLIT; ++sp)
      s += (double)ws[pb2 + (size_t)(b * NSPLIT + sp) * 64 + tid];
    b2s[tid] = s;
  } else if (tid < 68) {
    const int r = slice * 4 + (tid - 64);
    double s = 0.0;
    for (int sp = 0; sp < NSPLIT; ++sp)
      s += (double)ws[pa2 + (size_t)(b * NSPLIT + sp) * 64 + r];
    a2s[tid - 64] = s;
  }

  const int elem = slice * 256 + tid;   // 0..4095
  double acc = 0.0;
  for (int sp = 0; sp < NSPLIT; ++sp)
    acc += (double)ws[(size_t)(b * NSPLIT + sp) * 4096 + elem];
  __syncthreads();

  const int ii = tid >> 6;              // row within slice
  const int j = tid & 63;
  const double c2 = a2s[ii] + b2s[j] - 2.0 * acc;
  costg[(size_t)b * 4096 + elem] = sqrt(c2 > 0.0 ? c2 : 0.0);
}

// ---------------------------------------------------------------------------
// Kernel 3: pure solver. 16 blocks x 64 threads (1 wave). Cost in LDS.
// Col-reduction init + greedy, JV reduction transfer, Augmenting Row
// Reduction (chain cap 8, 2 passes), register Dijkstra. Exact min via the
// branchless 6-level 64-bit DPP reduce (round-7 proven). First-index
// tie-break == argmin. um/addu hoisted off the reduce's dependent chain.
// ---------------------------------------------------------------------------
__device__ __forceinline__ double readlane_d(double x, int lane) {
  const int lo = __builtin_amdgcn_readlane(__double2loint(x), lane);
  const int hi = __builtin_amdgcn_readlane(__double2hiint(x), lane);
  return __hiloint2double(hi, lo);
}

template <int CTRL, int RMASK>
__device__ __forceinline__ unsigned long long dpp_min_step(unsigned long long k) {
  const unsigned ohi = (unsigned)__builtin_amdgcn_update_dpp(
      -1, (int)(unsigned)(k >> 32), CTRL, RMASK, 0xf, false);
  const unsigned olo = (unsigned)__builtin_amdgcn_update_dpp(
      -1, (int)(unsigned)k, CTRL, RMASK, 0xf, false);
  const unsigned long long o = ((unsigned long long)ohi << 32) | olo;
  return o < k ? o : k;
}

__device__ __forceinline__ unsigned long long pack_key(double x) {
  const unsigned long long cb = (unsigned long long)__double_as_longlong(x);
  return cb ^ ((unsigned long long)((long long)cb >> 63) | 0x8000000000000000ULL);
}
__device__ __forceinline__ double unpack_key(unsigned long long k) {
  const unsigned long long SGN = 0x8000000000000000ULL;
  const unsigned long long mbits = (k & SGN) ? (k ^ SGN) : ~k;
  return __longlong_as_double((long long)mbits);
}
// 64-lane exact min of monotone-u64 keys, uniform result (branchless DPP)
__device__ __forceinline__ unsigned long long dpp_min64(unsigned long long k) {
  k = dpp_min_step<0x111, 0xf>(k);   // row_shr:1
  k = dpp_min_step<0x112, 0xf>(k);   // row_shr:2
  k = dpp_min_step<0x114, 0xf>(k);   // row_shr:4
  k = dpp_min_step<0x118, 0xf>(k);   // row_shr:8
  k = dpp_min_step<0x142, 0xa>(k);   // row_bcast:15
  k = dpp_min_step<0x143, 0xc>(k);   // row_bcast:31
  const unsigned hi = (unsigned)__builtin_amdgcn_readlane((int)(unsigned)(k >> 32), 63);
  const unsigned lo = (unsigned)__builtin_amdgcn_readlane((int)(unsigned)k, 63);
  return ((unsigned long long)hi << 32) | lo;
}

__global__ __launch_bounds__(64) void lsa_solve(const double* __restrict__ costg,
                                                int* __restrict__ out) {
  const int b = blockIdx.x;
  __shared__ double costd[64 * 64];
  const int tid = threadIdx.x;

  for (int e = tid; e < 4096; e += 64)
    costd[e] = costg[(size_t)b * 4096 + e];
  __syncthreads();

  const int l = tid;                 // lane l <-> column l+1, row l+1
  const double INFD = 1e30;

  // ---- column reduction: v[j] = min_i c[i,j]; greedy tight matching, u=0
  double cmin = costd[l];
  int cargmin = 0;
#pragma unroll 8
  for (int r = 1; r < 64; ++r) {
    const double cv = costd[r * 64 + l];
    if (cv < cmin) { cmin = cv; cargmin = r; }
  }
  double v_l = cmin;
  double u_l = 0.0;
  int p_l = 0;                       // row matched to column l+1 (0 = free)
  int colof_l = 0;                   // column matched to row l+1 (0 = free)
  unsigned long long rowused = 0ULL;
  for (int j = 0; j < 64; ++j) {
    const int rj = __builtin_amdgcn_readlane(cargmin, j);
    if (!((rowused >> rj) & 1ULL)) {
      rowused |= 1ULL << rj;
      if (l == j) p_l = rj + 1;
      if (l == rj) colof_l = j + 1;
    }
  }
  unsigned long long freemask = ~rowused;  // bit r-1 = row r unassigned

  // ---- JV reduction transfer: for each init-matched row ri (u was 0),
  // u[ri] = min_{j != j1}(c[ri][j] - v[j]); v[j1] -= u[ri].
  // rmin >= 0 (v is colmin), v only decreases, matched edges stay tight.
  {
    unsigned long long rm = rowused;
    while (rm) {
      const int ri = __ffsll(rm) - 1;          // 0-indexed matched row
      rm &= rm - 1;
      const int j1 = __builtin_amdgcn_readlane(colof_l, ri) - 1;  // its col
      const double red = costd[ri * 64 + l] - v_l;
      const unsigned long long k1 = (l == j1) ? pack_key(INFD) : pack_key(red);
      const unsigned long long mk = dpp_min64(k1);
      const double rmin = unpack_key(mk);
      if (l == ri) u_l = rmin;
      if (l == j1) v_l -= rmin;
    }
  }

  // ---- Augmenting Row Reduction (JV), chain cap 8, 2 passes
  for (int pass = 0; pass < 2; ++pass) {
    unsigned long long m = freemask;
    while (m) {
      int ir = __ffsll(m);           // 1-indexed free row
      m &= m - 1;
      for (int chain = 0; chain < 8; ++chain) {
        if (!((freemask >> (ir - 1)) & 1ULL)) break;
        const double cur = costd[(ir - 1) * 64 + l] - u_l * 0.0 - v_l;  // u[ir]=0 for free rows? no: use cur below
        // NOTE: free rows may carry u from reduction transfer only if they were
        // matched before — free rows here have u = 0 or stale u from a kick.
        // Use the row's current u (uniform readlane) for exactness.
        const double uir = readlane_d(u_l, ir - 1);
        const double curx = costd[(ir - 1) * 64 + l] - uir - v_l;
        (void)cur;
        const unsigned long long key1 = pack_key(curx);
        const unsigned long long mk1 = dpp_min64(key1);
        const double u1 = unpack_key(mk1);
        const int j1 = __ffsll(__ballot(key1 == mk1)) - 1;
        const unsigned long long key2 = (l == j1) ? pack_key(INFD) : key1;
        const unsigned long long mk2 = dpp_min64(key2);
        const double u2 = unpack_key(mk2);
        if (l == ir - 1) u_l = uir + u2;
        const bool strict = (u1 < u2);
        if (strict && l == j1) v_l -= (u2 - u1);
        const int k = __builtin_amdgcn_readlane(p_l, j1);  // occupant of col j1
        if (strict || k == 0) {
          if (l == j1) p_l = ir;
          if (l == ir - 1) colof_l = j1 + 1;
          freemask &= ~(1ULL << (ir - 1));
          if (k != 0) {
            if (l == k - 1) colof_l = 0;
            freemask |= 1ULL << (k - 1);
            if (strict) { ir = k; continue; }  // retry kicked row
          }
          break;
        } else {
          break;                     // tie & occupied: leave for Dijkstra
        }
      }
    }
  }

  // ---- shortest augmenting path for remaining free rows
  for (int i_row = 1; i_row <= 64; ++i_row) {
    if (!((freemask >> (i_row - 1)) & 1ULL)) continue;
    double minv = INFD;
    int way_l = 0;
    bool used = false;
    int j0 = 0;
    const bool irow_hit = (l + 1 == i_row);

    while (true) {
      const int i0 = (j0 == 0) ? i_row : __builtin_amdgcn_readlane(p_l, j0 - 1);
      if (i0 == 0) break;
      if (j0 > 0 && l == j0 - 1) used = true;
      // hoisted off the reduce chain: depends only on `used` and colof
      const unsigned long long um = __ballot(used);
      const bool addu = irow_hit ||
                        (colof_l != 0 && ((um >> (colof_l - 1)) & 1ULL));
      const double ui0 = readlane_d(u_l, i0 - 1);
      const double cur = costd[(i0 - 1) * 64 + l] - ui0 - v_l;
      if (!used && cur < minv) { minv = cur; way_l = j0; }
      const double cand = used ? INFD : minv;

      const unsigned long long key = pack_key(cand);
      const unsigned long long mkey = dpp_min64(key);
      const double delta = unpack_key(mkey);
      const int jmin = __ffsll(__ballot(key == mkey)) - 1;

      if (used) v_l -= delta; else minv -= delta;
      if (addu) u_l += delta;
      j0 = jmin + 1;
    }

    while (j0 != 0) {
      const int j1 = __builtin_amdgcn_readlane(way_l, j0 - 1);
      const int pj1 = (j1 == 0) ? i_row : __builtin_amdgcn_readlane(p_l, j1 - 1);
      if (l == j0 - 1) p_l = pj1;
      if (l == pj1 - 1) colof_l = j0;
      j0 = j1;
    }
  }

  out[b * NK + l] = l;                       // inds  (arange)
  out[NB * NK + b * NK + l] = colof_l - 1;   // inds2 (col of row l+1)
}

extern "C" void kernel_launch(void* const* d_in, const int* in_sizes, int n_in,
                              void* d_out, int out_size, void* d_ws, size_t ws_size,
                              hipStream_t stream) {
  const float* A = (const float*)d_in[0];   // outputs [16,64,50176] fp32
  const float* B = (const float*)d_in[1];   // targets [16,64,50176] fp32
  float* ws = (float*)d_ws;
  int* out = (int*)d_out;                   // 2048 int32: [inds | inds2]

  // floats used by partials: NB*NSPLIT*(4096+128); cost doubles appended.
  const size_t f112 = (size_t)NB * 112 * 4224;
  const size_t need112 = f112 * 4 + (size_t)NB * 4096 * 8;

  if (ws_size >= need112) {
    double* costg = (double*)(ws + f112);
    gemm_partial<112, 7><<<dim3(112, NB), 256, 0, stream>>>(A, B, ws);
    reduce_cost<112><<<dim3(16, NB), 256, 0, stream>>>(ws, costg);
    lsa_solve<<<NB, 64, 0, stream>>>(costg, out);
  } else {
    const size_t f49 = (size_t)NB * 49 * 4224;
    double* costg = (double*)(ws + f49);
    gemm_partial<49, 16><<<dim3(49, NB), 256, 0, stream>>>(A, B, ws);
    reduce_cost<49><<<dim3(16, NB), 256, 0, stream>>>(ws, costg);
    lsa_solve<<<NB, 64, 0, stream>>>(costg, out);
  }
}

// Round 10
// 286.602 us; speedup vs baseline: 1.4407x; 1.2079x over previous
//
#include <hip/hip_runtime.h>

#define DD 50176          // h*w
#define NB 16             // batches
#define NK 64             // k masks
#define TK 64             // k-tile width

// ---------------------------------------------------------------------------
// Kernel 1: split-K partial GEMM, 256 threads, 4x4 register tile/thread.
// T14 register double-buffer; norms accumulated from staging registers.
// LDS transposed [kk][col] with granule skew col=(row+4*(kk>>2))&63.
// ---------------------------------------------------------------------------
template <int NSPLIT, int NTILE>
__global__ __launch_bounds__(256) void gemm_partial(const float* __restrict__ A,
                                                    const float* __restrict__ B,
                                                    float* __restrict__ ws) {
  const int s = blockIdx.x;     // split
  const int b = blockIdx.y;     // batch
  const float* Ab = A + (size_t)b * NK * DD;
  const float* Bb = B + (size_t)b * NK * DD;
  __shared__ float As[TK * 64];
  __shared__ float Bs[TK * 64];
  const int tid = threadIdx.x;
  const int ti = tid & 15;      // output row-quad
  const int tj = tid >> 4;      // output col-quad
  const int kq = tid & 15;      // staging: k-granule 0..15
  const int r0 = tid >> 4;      // staging: row base 0..15

  float c[4][4] = {{0.f, 0.f, 0.f, 0.f}, {0.f, 0.f, 0.f, 0.f},
                   {0.f, 0.f, 0.f, 0.f}, {0.f, 0.f, 0.f, 0.f}};
  float a2p[4] = {0.f, 0.f, 0.f, 0.f};
  float b2p[4] = {0.f, 0.f, 0.f, 0.f};
  float4 avr[4], bvr[4];

  {
    const int k0 = s * NTILE * TK;
#pragma unroll
    for (int f = 0; f < 4; ++f) {
      const int r = f * 16 + r0;
      avr[f] = *reinterpret_cast<const float4*>(Ab + (size_t)r * DD + k0 + kq * 4);
      bvr[f] = *reinterpret_cast<const float4*>(Bb + (size_t)r * DD + k0 + kq * 4);
    }
  }

  for (int t = 0; t < NTILE; ++t) {
    __syncthreads();
#pragma unroll
    for (int f = 0; f < 4; ++f) {
      const int r = f * 16 + r0;
      const int col = (r + 4 * kq) & 63;
      const float4 av = avr[f];
      const float4 bv = bvr[f];
      As[(kq * 4 + 0) * 64 + col] = av.x;
      As[(kq * 4 + 1) * 64 + col] = av.y;
      As[(kq * 4 + 2) * 64 + col] = av.z;
      As[(kq * 4 + 3) * 64 + col] = av.w;
      Bs[(kq * 4 + 0) * 64 + col] = bv.x;
      Bs[(kq * 4 + 1) * 64 + col] = bv.y;
      Bs[(kq * 4 + 2) * 64 + col] = bv.z;
      Bs[(kq * 4 + 3) * 64 + col] = bv.w;
      a2p[f] = fmaf(av.x, av.x, a2p[f]); a2p[f] = fmaf(av.y, av.y, a2p[f]);
      a2p[f] = fmaf(av.z, av.z, a2p[f]); a2p[f] = fmaf(av.w, av.w, a2p[f]);
      b2p[f] = fmaf(bv.x, bv.x, b2p[f]); b2p[f] = fmaf(bv.y, bv.y, b2p[f]);
      b2p[f] = fmaf(bv.z, bv.z, b2p[f]); b2p[f] = fmaf(bv.w, bv.w, b2p[f]);
    }
    __syncthreads();

    if (t + 1 < NTILE) {
      const int k0 = (s * NTILE + t + 1) * TK;
#pragma unroll
      for (int f = 0; f < 4; ++f) {
        const int r = f * 16 + r0;
        avr[f] = *reinterpret_cast<const float4*>(Ab + (size_t)r * DD + k0 + kq * 4);
        bvr[f] = *reinterpret_cast<const float4*>(Bb + (size_t)r * DD + k0 + kq * 4);
      }
    }

#pragma unroll 8
    for (int kk = 0; kk < TK; ++kk) {
      const int g = 4 * (kk >> 2);
      const float4 a4 = *reinterpret_cast<const float4*>(&As[kk * 64 + ((4 * ti + g) & 63)]);
      const float4 b4 = *reinterpret_cast<const float4*>(&Bs[kk * 64 + ((4 * tj + g) & 63)]);
      const float ar[4] = {a4.x, a4.y, a4.z, a4.w};
      const float br[4] = {b4.x, b4.y, b4.z, b4.w};
#pragma unroll
      for (int r = 0; r < 4; ++r)
#pragma unroll
        for (int cc = 0; cc < 4; ++cc)
          c[r][cc] = fmaf(ar[r], br[cc], c[r][cc]);
    }
  }

  float* Pab = ws + (size_t)(b * NSPLIT + s) * 4096;
#pragma unroll
  for (int r = 0; r < 4; ++r) {
    *reinterpret_cast<float4*>(Pab + (ti * 4 + r) * 64 + tj * 4) =
        make_float4(c[r][0], c[r][1], c[r][2], c[r][3]);
  }

#pragma unroll
  for (int f = 0; f < 4; ++f) {
#pragma unroll
    for (int off = 1; off < 16; off <<= 1) {
      a2p[f] += __shfl_xor(a2p[f], off, 64);
      b2p[f] += __shfl_xor(b2p[f], off, 64);
    }
  }
  if (kq == 0) {
    float* Pa2 = ws + (size_t)NB * NSPLIT * 4096 + (size_t)(b * NSPLIT + s) * 64;
    float* Pb2 = Pa2 + (size_t)NB * NSPLIT * 64;
#pragma unroll
    for (int f = 0; f < 4; ++f) {
      Pa2[f * 16 + r0] = a2p[f];
      Pb2[f * 16 + r0] = b2p[f];
    }
  }
}

// ---------------------------------------------------------------------------
// Kernel 2: parallel cost build. 16 slices x 16 batches = 256 blocks.
// Internal reduction in double (split-K sums + a2+b2-2ab cancellation),
// final cost cast to fp32 for the solver.
// ---------------------------------------------------------------------------
template <int NSPLIT>
__global__ __launch_bounds__(256) void reduce_cost(const float* __restrict__ ws,
                                                   float* __restrict__ costg) {
  const int slice = blockIdx.x;  // 0..15
  const int b = blockIdx.y;
  const int tid = threadIdx.x;
  __shared__ double a2s[4], b2s[64];
  const size_t pa2 = (size_t)NB * NSPLIT * 4096;
  const size_t pb2 = pa2 + (size_t)NB * NSPLIT * 64;

  if (tid < 64) {
    double s = 0.0;
    for (int sp = 0; sp < NSPLIT; ++sp)
      s += (double)ws[pb2 + (size_t)(b * NSPLIT + sp) * 64 + tid];
    b2s[tid] = s;
  } else if (tid < 68) {
    const int r = slice * 4 + (tid - 64);
    double s = 0.0;
    for (int sp = 0; sp < NSPLIT; ++sp)
      s += (double)ws[pa2 + (size_t)(b * NSPLIT + sp) * 64 + r];
    a2s[tid - 64] = s;
  }

  const int elem = slice * 256 + tid;   // 0..4095
  double acc = 0.0;
  for (int sp = 0; sp < NSPLIT; ++sp)
    acc += (double)ws[(size_t)(b * NSPLIT + sp) * 4096 + elem];
  __syncthreads();

  const int ii = tid >> 6;              // row within slice
  const int j = tid & 63;
  const double c2 = a2s[ii] + b2s[j] - 2.0 * acc;
  costg[(size_t)b * 4096 + elem] = (float)sqrt(c2 > 0.0 ? c2 : 0.0);
}

// ---------------------------------------------------------------------------
// Kernel 3: pure solver, fp32 throughout. 16 blocks x 64 threads (1 wave).
// Cost in LDS (16KB). Col-reduction init + greedy, JV reduction transfer,
// Augmenting Row Reduction (chain cap 8, 2 passes), register Dijkstra.
// Wave min via 6-level v_min_f32 + DPP (identity lane = +inf); min result is
// bit-exact to the winner's value, so ballot(cand==m)+ffs keeps the
// first-index argmin tie-break.
// ---------------------------------------------------------------------------
__device__ __forceinline__ float readlane_f(float x, int lane) {
  return __int_as_float(__builtin_amdgcn_readlane(__float_as_int(x), lane));
}

template <int CTRL, int RMASK>
__device__ __forceinline__ float dpp_minf_step(float k) {
  const float o = __int_as_float(__builtin_amdgcn_update_dpp(
      0x7F800000 /* +inf: min identity for invalid lanes */,
      __float_as_int(k), CTRL, RMASK, 0xf, false));
  return fminf(o, k);
}
// 64-lane fp32 min, uniform result
__device__ __forceinline__ float dpp_minf(float k) {
  k = dpp_minf_step<0x111, 0xf>(k);   // row_shr:1
  k = dpp_minf_step<0x112, 0xf>(k);   // row_shr:2
  k = dpp_minf_step<0x114, 0xf>(k);   // row_shr:4
  k = dpp_minf_step<0x118, 0xf>(k);   // row_shr:8
  k = dpp_minf_step<0x142, 0xa>(k);   // row_bcast:15
  k = dpp_minf_step<0x143, 0xc>(k);   // row_bcast:31
  return readlane_f(k, 63);
}

__global__ __launch_bounds__(64) void lsa_solve(const float* __restrict__ costg,
                                                int* __restrict__ out) {
  const int b = blockIdx.x;
  __shared__ float costd[64 * 64];
  const int tid = threadIdx.x;

  for (int e = tid; e < 4096; e += 64)
    costd[e] = costg[(size_t)b * 4096 + e];
  __syncthreads();

  const int l = tid;                 // lane l <-> column l+1, row l+1
  const float INFF = 1e30f;

  // ---- column reduction: v[j] = min_i c[i,j]; greedy tight matching, u=0
  float cmin = costd[l];
  int cargmin = 0;
#pragma unroll 8
  for (int r = 1; r < 64; ++r) {
    const float cv = costd[r * 64 + l];
    if (cv < cmin) { cmin = cv; cargmin = r; }
  }
  float v_l = cmin;
  float u_l = 0.0f;
  int p_l = 0;                       // row matched to column l+1 (0 = free)
  int colof_l = 0;                   // column matched to row l+1 (0 = free)
  unsigned long long rowused = 0ULL;
  for (int j = 0; j < 64; ++j) {
    const int rj = __builtin_amdgcn_readlane(cargmin, j);
    if (!((rowused >> rj) & 1ULL)) {
      rowused |= 1ULL << rj;
      if (l == j) p_l = rj + 1;
      if (l == rj) colof_l = j + 1;
    }
  }
  unsigned long long freemask = ~rowused;  // bit r-1 = row r unassigned

  // ---- JV reduction transfer: for each init-matched row ri (u was 0),
  // u[ri] = min_{j != j1}(c[ri][j] - v[j]); v[j1] -= u[ri].
  {
    unsigned long long rm = rowused;
    while (rm) {
      const int ri = __ffsll(rm) - 1;          // 0-indexed matched row
      rm &= rm - 1;
      const int j1 = __builtin_amdgcn_readlane(colof_l, ri) - 1;  // its col
      const float red = (l == j1) ? INFF : (costd[ri * 64 + l] - v_l);
      const float rmin = dpp_minf(red);
      if (l == ri) u_l = rmin;
      if (l == j1) v_l -= rmin;
    }
  }

  // ---- Augmenting Row Reduction (JV), chain cap 8, 2 passes
  for (int pass = 0; pass < 2; ++pass) {
    unsigned long long m = freemask;
    while (m) {
      int ir = __ffsll(m);           // 1-indexed free row
      m &= m - 1;
      for (int chain = 0; chain < 8; ++chain) {
        if (!((freemask >> (ir - 1)) & 1ULL)) break;
        const float uir = readlane_f(u_l, ir - 1);
        const float curx = costd[(ir - 1) * 64 + l] - uir - v_l;
        const float u1 = dpp_minf(curx);
        const int j1 = __ffsll(__ballot(curx == u1)) - 1;
        const float cur2 = (l == j1) ? INFF : curx;
        const float u2 = dpp_minf(cur2);
        if (l == ir - 1) u_l = uir + u2;
        const bool strict = (u1 < u2);
        if (strict && l == j1) v_l -= (u2 - u1);
        const int k = __builtin_amdgcn_readlane(p_l, j1);  // occupant of col j1
        if (strict || k == 0) {
          if (l == j1) p_l = ir;
          if (l == ir - 1) colof_l = j1 + 1;
          freemask &= ~(1ULL << (ir - 1));
          if (k != 0) {
            if (l == k - 1) colof_l = 0;
            freemask |= 1ULL << (k - 1);
            if (strict) { ir = k; continue; }  // retry kicked row
          }
          break;
        } else {
          break;                     // tie & occupied: leave for Dijkstra
        }
      }
    }
  }

  // ---- shortest augmenting path for remaining free rows
  for (int i_row = 1; i_row <= 64; ++i_row) {
    if (!((freemask >> (i_row - 1)) & 1ULL)) continue;
    float minv = INFF;
    int way_l = 0;
    bool used = false;
    int j0 = 0;
    const bool irow_hit = (l + 1 == i_row);

    while (true) {
      const int i0 = (j0 == 0) ? i_row : __builtin_amdgcn_readlane(p_l, j0 - 1);
      if (i0 == 0) break;
      if (j0 > 0 && l == j0 - 1) used = true;
      // off the reduce chain: depends only on `used` and colof
      const unsigned long long um = __ballot(used);
      const bool addu = irow_hit ||
                        (colof_l != 0 && ((um >> (colof_l - 1)) & 1ULL));
      const float ui0 = readlane_f(u_l, i0 - 1);
      const float cur = costd[(i0 - 1) * 64 + l] - ui0 - v_l;
      if (!used && cur < minv) { minv = cur; way_l = j0; }
      const float cand = used ? INFF : minv;

      const float delta = dpp_minf(cand);
      const int jmin = __ffsll(__ballot(cand == delta)) - 1;

      if (used) v_l -= delta; else minv -= delta;
      if (addu) u_l += delta;
      j0 = jmin + 1;
    }

    while (j0 != 0) {
      const int j1 = __builtin_amdgcn_readlane(way_l, j0 - 1);
      const int pj1 = (j1 == 0) ? i_row : __builtin_amdgcn_readlane(p_l, j1 - 1);
      if (l == j0 - 1) p_l = pj1;
      if (l == pj1 - 1) colof_l = j0;
      j0 = j1;
    }
  }

  out[b * NK + l] = l;                       // inds  (arange)
  out[NB * NK + b * NK + l] = colof_l - 1;   // inds2 (col of row l+1)
}

extern "C" void kernel_launch(void* const* d_in, const int* in_sizes, int n_in,
                              void* d_out, int out_size, void* d_ws, size_t ws_size,
                              hipStream_t stream) {
  const float* A = (const float*)d_in[0];   // outputs [16,64,50176] fp32
  const float* B = (const float*)d_in[1];   // targets [16,64,50176] fp32
  float* ws = (float*)d_ws;
  int* out = (int*)d_out;                   // 2048 int32: [inds | inds2]

  // floats used by partials: NB*NSPLIT*(4096+128); cost floats appended.
  const size_t f112 = (size_t)NB * 112 * 4224;
  const size_t need112 = (f112 + (size_t)NB * 4096) * 4;

  if (ws_size >= need112) {
    float* costg = ws + f112;
    gemm_partial<112, 7><<<dim3(112, NB), 256, 0, stream>>>(A, B, ws);
    reduce_cost<112><<<dim3(16, NB), 256, 0, stream>>>(ws, costg);
    lsa_solve<<<NB, 64, 0, stream>>>(costg, out);
  } else {
    const size_t f49 = (size_t)NB * 49 * 4224;
    float* costg = ws + f49;
    gemm_partial<49, 16><<<dim3(49, NB), 256, 0, stream>>>(A, B, ws);
    reduce_cost<49><<<dim3(16, NB), 256, 0, stream>>>(ws, costg);
    lsa_solve<<<NB, 64, 0, stream>>>(costg, out);
  }
}

// Round 11
// 264.620 us; speedup vs baseline: 1.5604x; 1.0831x over previous
//
#include <hip/hip_runtime.h>

#define DD 50176          // h*w
#define NB 16             // batches
#define NK 64             // k masks

constexpr int KSPLIT = 64;   // splits per batch (16 blocks x 4 waves)
constexpr int KTILE  = 49;   // 16-wide k-tiles per split (49*16=784; 64*784=50176)
constexpr int TKK    = 16;   // kk per tile

// ---------------------------------------------------------------------------
// Kernel 1: split-K partial GEMM. 4 independent waves per block, each wave
// owns a private k-slice + private 8KB LDS slice -> NO __syncthreads (in-wave
// lgkmcnt ordering only). 8x8 register tile per lane (wave = full 64x64 tile)
// -> 1 B LDS / FLOP (half of the 4x4 scheme; LDS pipe was the binding
// resource). T14 register double-buffer for staging; norms from staging regs.
// LDS transposed [kk][col] with skew col=(row+8*(kk>>2))&63: staging ds_write
// 2-way, paired ds_read_b128 2-way (both ~free per m136).
// Grid 16x16 = 256 blocks = 1/CU, perfectly balanced.
// ---------------------------------------------------------------------------
__global__ __launch_bounds__(256) void gemm_partial(const float* __restrict__ A,
                                                    const float* __restrict__ B,
                                                    float* __restrict__ ws) {
  const int b = blockIdx.y;
  const int w = threadIdx.x >> 6;        // wave 0..3
  const int lane = threadIdx.x & 63;
  const int s = blockIdx.x * 4 + w;      // split 0..63
  const float* Ab = A + (size_t)b * NK * DD;
  const float* Bb = B + (size_t)b * NK * DD;

  __shared__ __align__(16) float lds[4][2][TKK * 64];  // [wave][A|B][kk][col]
  float* As = lds[w][0];
  float* Bs = lds[w][1];

  const int ti = lane >> 3;              // output row-octet 0..7
  const int tj = lane & 7;               // output col-octet 0..7
  const int kq = lane & 3;               // staging k-granule (4 floats)
  const int rr = lane >> 2;              // staging row-in-group 0..15

  float c[8][8];
#pragma unroll
  for (int r = 0; r < 8; ++r)
#pragma unroll
    for (int q = 0; q < 8; ++q) c[r][q] = 0.f;
  float a2p[4] = {0.f, 0.f, 0.f, 0.f};
  float b2p[4] = {0.f, 0.f, 0.f, 0.f};
  float4 avr[4], bvr[4];

  const int kbase = s * (KTILE * TKK);
  // prologue: load tile 0 into registers
#pragma unroll
  for (int f = 0; f < 4; ++f) {
    const int row = f * 16 + rr;
    avr[f] = *reinterpret_cast<const float4*>(Ab + (size_t)row * DD + kbase + kq * 4);
    bvr[f] = *reinterpret_cast<const float4*>(Bb + (size_t)row * DD + kbase + kq * 4);
  }

  for (int t = 0; t < KTILE; ++t) {
    // stage regs -> LDS (transpose + skew); accumulate norms from regs
#pragma unroll
    for (int f = 0; f < 4; ++f) {
      const int row = f * 16 + rr;
      const int col = (row + 8 * kq) & 63;
      const float4 av = avr[f], bv = bvr[f];
      As[(kq * 4 + 0) * 64 + col] = av.x;
      As[(kq * 4 + 1) * 64 + col] = av.y;
      As[(kq * 4 + 2) * 64 + col] = av.z;
      As[(kq * 4 + 3) * 64 + col] = av.w;
      Bs[(kq * 4 + 0) * 64 + col] = bv.x;
      Bs[(kq * 4 + 1) * 64 + col] = bv.y;
      Bs[(kq * 4 + 2) * 64 + col] = bv.z;
      Bs[(kq * 4 + 3) * 64 + col] = bv.w;
      a2p[f] = fmaf(av.x, av.x, a2p[f]); a2p[f] = fmaf(av.y, av.y, a2p[f]);
      a2p[f] = fmaf(av.z, av.z, a2p[f]); a2p[f] = fmaf(av.w, av.w, a2p[f]);
      b2p[f] = fmaf(bv.x, bv.x, b2p[f]); b2p[f] = fmaf(bv.y, bv.y, b2p[f]);
      b2p[f] = fmaf(bv.z, bv.z, b2p[f]); b2p[f] = fmaf(bv.w, bv.w, b2p[f]);
    }
    // T14: issue next tile's global loads; drain under this tile's compute
    if (t + 1 < KTILE) {
      const int k0 = kbase + (t + 1) * TKK;
#pragma unroll
      for (int f = 0; f < 4; ++f) {
        const int row = f * 16 + rr;
        avr[f] = *reinterpret_cast<const float4*>(Ab + (size_t)row * DD + k0 + kq * 4);
        bvr[f] = *reinterpret_cast<const float4*>(Bb + (size_t)row * DD + k0 + kq * 4);
      }
    }
    // compute: 16 kk x 64 FMA per lane
#pragma unroll 4
    for (int kk = 0; kk < TKK; ++kk) {
      const int g = 8 * (kk >> 2);
      const float4 a0 = *reinterpret_cast<const float4*>(&As[kk * 64 + ((8 * ti + g) & 63)]);
      const float4 a1 = *reinterpret_cast<const float4*>(&As[kk * 64 + ((8 * ti + 4 + g) & 63)]);
      const float4 b0 = *reinterpret_cast<const float4*>(&Bs[kk * 64 + ((8 * tj + g) & 63)]);
      const float4 b1 = *reinterpret_cast<const float4*>(&Bs[kk * 64 + ((8 * tj + 4 + g) & 63)]);
      const float ar[8] = {a0.x, a0.y, a0.z, a0.w, a1.x, a1.y, a1.z, a1.w};
      const float br[8] = {b0.x, b0.y, b0.z, b0.w, b1.x, b1.y, b1.z, b1.w};
#pragma unroll
      for (int r = 0; r < 8; ++r)
#pragma unroll
        for (int q = 0; q < 8; ++q)
          c[r][q] = fmaf(ar[r], br[q], c[r][q]);
    }
  }

  float* Pab = ws + (size_t)(b * KSPLIT + s) * 4096;
#pragma unroll
  for (int r = 0; r < 8; ++r) {
    *reinterpret_cast<float4*>(Pab + (8 * ti + r) * 64 + 8 * tj) =
        make_float4(c[r][0], c[r][1], c[r][2], c[r][3]);
    *reinterpret_cast<float4*>(Pab + (8 * ti + r) * 64 + 8 * tj + 4) =
        make_float4(c[r][4], c[r][5], c[r][6], c[r][7]);
  }

  // reduce norm partials across the 4 kq lanes of each row-group
#pragma unroll
  for (int f = 0; f < 4; ++f) {
    a2p[f] += __shfl_xor(a2p[f], 1, 64);
    a2p[f] += __shfl_xor(a2p[f], 2, 64);
    b2p[f] += __shfl_xor(b2p[f], 1, 64);
    b2p[f] += __shfl_xor(b2p[f], 2, 64);
  }
  if (kq == 0) {                         // 16 lanes, rr = 0..15
    float* Pa2 = ws + (size_t)NB * KSPLIT * 4096 + (size_t)(b * KSPLIT + s) * 64;
    float* Pb2 = Pa2 + (size_t)NB * KSPLIT * 64;
#pragma unroll
    for (int f = 0; f < 4; ++f) {
      Pa2[f * 16 + rr] = a2p[f];
      Pb2[f * 16 + rr] = b2p[f];
    }
  }
}

// ---------------------------------------------------------------------------
// Kernel 2: parallel cost build. 16 slices x 16 batches = 256 blocks.
// Internal reduction in double (split-K sums + a2+b2-2ab cancellation),
// final cost cast to fp32 for the solver.
// ---------------------------------------------------------------------------
template <int NSPLIT>
__global__ __launch_bounds__(256) void reduce_cost(const float* __restrict__ ws,
                                                   float* __restrict__ costg) {
  const int slice = blockIdx.x;  // 0..15
  const int b = blockIdx.y;
  const int tid = threadIdx.x;
  __shared__ double a2s[4], b2s[64];
  const size_t pa2 = (size_t)NB * NSPLIT * 4096;
  const size_t pb2 = pa2 + (size_t)NB * NSPLIT * 64;

  if (tid < 64) {
    double s = 0.0;
    for (int sp = 0; sp < NSPLIT; ++sp)
      s += (double)ws[pb2 + (size_t)(b * NSPLIT + sp) * 64 + tid];
    b2s[tid] = s;
  } else if (tid < 68) {
    const int r = slice * 4 + (tid - 64);
    double s = 0.0;
    for (int sp = 0; sp < NSPLIT; ++sp)
      s += (double)ws[pa2 + (size_t)(b * NSPLIT + sp) * 64 + r];
    a2s[tid - 64] = s;
  }

  const int elem = slice * 256 + tid;   // 0..4095
  double acc = 0.0;
  for (int sp = 0; sp < NSPLIT; ++sp)
    acc += (double)ws[(size_t)(b * NSPLIT + sp) * 4096 + elem];
  __syncthreads();

  const int ii = tid >> 6;              // row within slice
  const int j = tid & 63;
  const double c2 = a2s[ii] + b2s[j] - 2.0 * acc;
  costg[(size_t)b * 4096 + elem] = (float)sqrt(c2 > 0.0 ? c2 : 0.0);
}

// ---------------------------------------------------------------------------
// Kernel 3: pure solver, fp32 throughout (round-10 proven). 16 blocks x 1 wave.
// Col-reduction init + greedy, JV reduction transfer, Augmenting Row
// Reduction (chain cap 8, 2 passes), register Dijkstra. Wave min via 6-level
// v_min_f32 + DPP; ballot(cand==m)+ffs keeps first-index argmin tie-break.
// ---------------------------------------------------------------------------
__device__ __forceinline__ float readlane_f(float x, int lane) {
  return __int_as_float(__builtin_amdgcn_readlane(__float_as_int(x), lane));
}

template <int CTRL, int RMASK>
__device__ __forceinline__ float dpp_minf_step(float k) {
  const float o = __int_as_float(__builtin_amdgcn_update_dpp(
      0x7F800000 /* +inf: min identity for invalid lanes */,
      __float_as_int(k), CTRL, RMASK, 0xf, false));
  return fminf(o, k);
}
// 64-lane fp32 min, uniform result
__device__ __forceinline__ float dpp_minf(float k) {
  k = dpp_minf_step<0x111, 0xf>(k);   // row_shr:1
  k = dpp_minf_step<0x112, 0xf>(k);   // row_shr:2
  k = dpp_minf_step<0x114, 0xf>(k);   // row_shr:4
  k = dpp_minf_step<0x118, 0xf>(k);   // row_shr:8
  k = dpp_minf_step<0x142, 0xa>(k);   // row_bcast:15
  k = dpp_minf_step<0x143, 0xc>(k);   // row_bcast:31
  return readlane_f(k, 63);
}

__global__ __launch_bounds__(64) void lsa_solve(const float* __restrict__ costg,
                                                int* __restrict__ out) {
  const int b = blockIdx.x;
  __shared__ float costd[64 * 64];
  const int tid = threadIdx.x;

  for (int e = tid; e < 4096; e += 64)
    costd[e] = costg[(size_t)b * 4096 + e];
  __syncthreads();

  const int l = tid;                 // lane l <-> column l+1, row l+1
  const float INFF = 1e30f;

  // ---- column reduction: v[j] = min_i c[i,j]; greedy tight matching, u=0
  float cmin = costd[l];
  int cargmin = 0;
#pragma unroll 8
  for (int r = 1; r < 64; ++r) {
    const float cv = costd[r * 64 + l];
    if (cv < cmin) { cmin = cv; cargmin = r; }
  }
  float v_l = cmin;
  float u_l = 0.0f;
  int p_l = 0;                       // row matched to column l+1 (0 = free)
  int colof_l = 0;                   // column matched to row l+1 (0 = free)
  unsigned long long rowused = 0ULL;
  for (int j = 0; j < 64; ++j) {
    const int rj = __builtin_amdgcn_readlane(cargmin, j);
    if (!((rowused >> rj) & 1ULL)) {
      rowused |= 1ULL << rj;
      if (l == j) p_l = rj + 1;
      if (l == rj) colof_l = j + 1;
    }
  }
  unsigned long long freemask = ~rowused;  // bit r-1 = row r unassigned

  // ---- JV reduction transfer
  {
    unsigned long long rm = rowused;
    while (rm) {
      const int ri = __ffsll(rm) - 1;          // 0-indexed matched row
      rm &= rm - 1;
      const int j1 = __builtin_amdgcn_readlane(colof_l, ri) - 1;  // its col
      const float red = (l == j1) ? INFF : (costd[ri * 64 + l] - v_l);
      const float rmin = dpp_minf(red);
      if (l == ri) u_l = rmin;
      if (l == j1) v_l -= rmin;
    }
  }

  // ---- Augmenting Row Reduction (JV), chain cap 8, 2 passes
  for (int pass = 0; pass < 2; ++pass) {
    unsigned long long m = freemask;
    while (m) {
      int ir = __ffsll(m);           // 1-indexed free row
      m &= m - 1;
      for (int chain = 0; chain < 8; ++chain) {
        if (!((freemask >> (ir - 1)) & 1ULL)) break;
        const float uir = readlane_f(u_l, ir - 1);
        const float curx = costd[(ir - 1) * 64 + l] - uir - v_l;
        const float u1 = dpp_minf(curx);
        const int j1 = __ffsll(__ballot(curx == u1)) - 1;
        const float cur2 = (l == j1) ? INFF : curx;
        const float u2 = dpp_minf(cur2);
        if (l == ir - 1) u_l = uir + u2;
        const bool strict = (u1 < u2);
        if (strict && l == j1) v_l -= (u2 - u1);
        const int k = __builtin_amdgcn_readlane(p_l, j1);  // occupant of col j1
        if (strict || k == 0) {
          if (l == j1) p_l = ir;
          if (l == ir - 1) colof_l = j1 + 1;
          freemask &= ~(1ULL << (ir - 1));
          if (k != 0) {
            if (l == k - 1) colof_l = 0;
            freemask |= 1ULL << (k - 1);
            if (strict) { ir = k; continue; }  // retry kicked row
          }
          break;
        } else {
          break;                     // tie & occupied: leave for Dijkstra
        }
      }
    }
  }

  // ---- shortest augmenting path for remaining free rows
  for (int i_row = 1; i_row <= 64; ++i_row) {
    if (!((freemask >> (i_row - 1)) & 1ULL)) continue;
    float minv = INFF;
    int way_l = 0;
    bool used = false;
    int j0 = 0;
    const bool irow_hit = (l + 1 == i_row);

    while (true) {
      const int i0 = (j0 == 0) ? i_row : __builtin_amdgcn_readlane(p_l, j0 - 1);
      if (i0 == 0) break;
      if (j0 > 0 && l == j0 - 1) used = true;
      // off the reduce chain: depends only on `used` and colof
      const unsigned long long um = __ballot(used);
      const bool addu = irow_hit ||
                        (colof_l != 0 && ((um >> (colof_l - 1)) & 1ULL));
      const float ui0 = readlane_f(u_l, i0 - 1);
      const float cur = costd[(i0 - 1) * 64 + l] - ui0 - v_l;
      if (!used && cur < minv) { minv = cur; way_l = j0; }
      const float cand = used ? INFF : minv;

      const float delta = dpp_minf(cand);
      const int jmin = __ffsll(__ballot(cand == delta)) - 1;

      if (used) v_l -= delta; else minv -= delta;
      if (addu) u_l += delta;
      j0 = jmin + 1;
    }

    while (j0 != 0) {
      const int j1 = __builtin_amdgcn_readlane(way_l, j0 - 1);
      const int pj1 = (j1 == 0) ? i_row : __builtin_amdgcn_readlane(p_l, j1 - 1);
      if (l == j0 - 1) p_l = pj1;
      if (l == pj1 - 1) colof_l = j0;
      j0 = j1;
    }
  }

  out[b * NK + l] = l;                       // inds  (arange)
  out[NB * NK + b * NK + l] = colof_l - 1;   // inds2 (col of row l+1)
}

extern "C" void kernel_launch(void* const* d_in, const int* in_sizes, int n_in,
                              void* d_out, int out_size, void* d_ws, size_t ws_size,
                              hipStream_t stream) {
  const float* A = (const float*)d_in[0];   // outputs [16,64,50176] fp32
  const float* B = (const float*)d_in[1];   // targets [16,64,50176] fp32
  float* ws = (float*)d_ws;
  int* out = (int*)d_out;                   // 2048 int32: [inds | inds2]

  // partials: NB*KSPLIT*(4096+128) floats ≈ 17.3 MB; cost floats appended.
  const size_t fpart = (size_t)NB * KSPLIT * 4224;
  float* costg = ws + fpart;

  gemm_partial<<<dim3(16, NB), 256, 0, stream>>>(A, B, ws);
  reduce_cost<KSPLIT><<<dim3(16, NB), 256, 0, stream>>>(ws, costg);
  lsa_solve<<<NB, 64, 0, stream>>>(costg, out);
}